// Round 6
// baseline (442.251 us; speedup 1.0000x reference)
//
#include <hip/hip_runtime.h>
#include <hip/hip_bf16.h>
#include <math.h>
#include <limits.h>

// ---- problem constants ----
#define C_IN 256
#define HM_H 136
#define HM_W 240
#define HM_N (HM_H * HM_W)      // 32640
#define MB   64
#define MH   272
#define MW   480
#define MN   (MH * MW)          // 130560
#define NP   134
#define NI   4
#define HID  64
#define PW   484                // padded width of T (pixel-major bf16 tensor)
#define PH   276                // 274 used + 2 slack rows for DMA overshoot

// d_out layout (floats): scores[4] | inds[4] | regs0[4*MN] | masks0[4*MN] | feat[4*480*2]
#define REG_OFF   8
#define MASK_OFF  (8 + NI * MN)
#define FEAT_OFF  (8 + 2 * NI * MN)

// ws layout (floats) — NON-OVERLAPPING (R5 bug: wt overlapped gp/inds/cnt)
#define WS_HM   0                         // 32640
#define WS_CV   HM_N                      // 512 cand values
#define WS_CI   (HM_N + 512)              // 512 cand indices
#define WS_GP   (2 * HM_N)                // 536 gen params   [65280,65816)
#define WS_INDS (2 * HM_N + NI * NP)      // 4 ints           [65816,65820)
#define WS_CNT  (WS_INDS + 4)             // 1 uint ticket    [65820,65821)
#define WS_WT_F 65824                     // wt: 147456 ushorts = 73728 floats [65824,139552)
#define WS_T_F  139552                    // T: 276*484*256 ushorts = 17096832 floats

typedef float  f32x4  __attribute__((ext_vector_type(4)));
typedef short  bf16x8 __attribute__((ext_vector_type(8)));

#define AS1 __attribute__((address_space(1)))
#define AS3 __attribute__((address_space(3)))

__device__ __forceinline__ unsigned short f2bf(float f) {
  unsigned int u = __float_as_uint(f);
  u += 0x7FFFu + ((u >> 16) & 1u);
  return (unsigned short)(u >> 16);
}
__device__ __forceinline__ float b2f(unsigned short h) {
  return __uint_as_float(((unsigned int)h) << 16);
}
__device__ __forceinline__ unsigned int pkbf2(float lo, float hi) {
  __hip_bfloat162 h = __float22bfloat162_rn(make_float2(lo, hi));
  return *(unsigned int*)&h;
}

// direct global->LDS DMA, 16 B per lane, LDS dest = wave-uniform base + lane*16
__device__ __forceinline__ void dma16(const unsigned short* g, unsigned short* l) {
  __builtin_amdgcn_global_load_lds((const AS1 unsigned int*)g, (AS3 unsigned int*)l, 16, 0, 0);
}

// ------------------------------------------------------------------
// K_pre: fused (a) weight swizzle, (b) hm head, (c) out0 -> T bf16 transpose,
// (d) T pad-ring zeroing, (e) ticket counter reset.
// block ranges: [0,576) wswz | [576,1086) hm | [1086,1596) transpose | [1596,1785) pad
// ------------------------------------------------------------------
__global__ void k_pre(const float* __restrict__ mb_w, unsigned short* __restrict__ wt,
                      const float* __restrict__ out1, const float* __restrict__ hm_w,
                      const float* __restrict__ hm_b, float* __restrict__ ws_hm,
                      const float* __restrict__ out0, unsigned short* __restrict__ T,
                      unsigned int* __restrict__ cnt) {
  __shared__ float part[4][64];
  int b = blockIdx.x, t = threadIdx.x;
  if (b == 0 && t == 0) *cnt = 0;
  if (b < 576) {
    int idx = b * 256 + t;                 // 147456 total
    int j    = idx & 7;
    int lane = (idx >> 3) & 63;
    int nt   = (idx >> 9) & 3;
    int gt   = idx >> 11;
    int tp   = gt % 9;
    int g    = gt / 9;
    int n = nt * 16 + (lane & 15);
    int c = g * 32 + (lane >> 4) * 8 + j;
    wt[idx] = f2bf(mb_w[(n * C_IN + c) * 9 + tp]);
  } else if (b < 1086) {
    int bb = b - 576;                      // 510 blocks
    int cg = t >> 6, pl = t & 63;
    int p = bb * 64 + pl;
    float s = 0.f;
    #pragma unroll 16
    for (int c = 0; c < 64; ++c)
      s += hm_w[cg * 64 + c] * out1[(cg * 64 + c) * HM_N + p];
    part[cg][pl] = s;
    __syncthreads();
    if (t < 64) {
      float tot = part[0][t] + part[1][t] + part[2][t] + part[3][t] + hm_b[0];
      float sig = 1.f / (1.f + expf(-tot));
      sig = fminf(fmaxf(sig, 1e-4f), 1.f - 1e-4f);
      ws_hm[bb * 64 + t] = sig;
    }
  } else if (b < 1596) {
    // transpose: thread owns pixel p; 32 octets of 8 channels each
    int p = (b - 1086) * 256 + t;          // 510*256 = 130560
    int y = p / MW, x = p - y * MW;
    const float* base = out0 + p;
    unsigned short* dst = T + (size_t)((y + 1) * PW + (x + 1)) * 256;
    #pragma unroll 2
    for (int oct = 0; oct < 32; ++oct) {
      const float* s8 = base + oct * 8 * MN;
      float v0 = s8[0], v1 = s8[MN], v2 = s8[2*MN], v3 = s8[3*MN];
      float v4 = s8[4*MN], v5 = s8[5*MN], v6 = s8[6*MN], v7 = s8[7*MN];
      uint4 pk;
      pk.x = pkbf2(v0, v1); pk.y = pkbf2(v2, v3);
      pk.z = pkbf2(v4, v5); pk.w = pkbf2(v6, v7);
      *(uint4*)(dst + oct * 8) = pk;
    }
  } else {
    // zero the pad ring: rows 0 & 273 (484 px) + cols 0,481 for rows 1..272 (544 px)
    int i = (b - 1596) * 256 + t;          // 1512 px * 32 uint4 = 48384
    if (i < 48384) {
      int z = i >> 5, q = i & 31;
      int trow, tcol;
      if (z < 484)      { trow = 0;   tcol = z; }
      else if (z < 968) { trow = 273; tcol = z - 484; }
      else {
        int zz = z - 968;                  // 0..543
        trow = 1 + (zz >> 1);
        tcol = (zz & 1) ? 481 : 0;
      }
      *(uint4*)(T + (size_t)(trow * PW + tcol) * 256 + q * 8) = make_uint4(0, 0, 0, 0);
    }
  }
}

// ------------------------------------------------------------------
// top-4 helpers
// ------------------------------------------------------------------
__device__ __forceinline__ bool better(float av, int ai, float bv, int bi) {
  return (av > bv) || (av == bv && ai < bi);
}

template<int NTHR>
__device__ void top4_tree(float* sv, int* si, int t) {
  for (int s = NTHR / 2; s >= 1; s >>= 1) {
    if (t < s) {
      float a[4], b[4]; int ai[4], bj[4];
      #pragma unroll
      for (int k = 0; k < 4; ++k) {
        a[k] = sv[t * 4 + k];        ai[k] = si[t * 4 + k];
        b[k] = sv[(t + s) * 4 + k];  bj[k] = si[(t + s) * 4 + k];
      }
      float ov[4]; int oi[4];
      int i = 0, j = 0;
      #pragma unroll
      for (int k = 0; k < 4; ++k) {
        if (better(a[i], ai[i], b[j], bj[j])) { ov[k] = a[i]; oi[k] = ai[i]; ++i; }
        else                                   { ov[k] = b[j]; oi[k] = bj[j]; ++j; }
      }
      #pragma unroll
      for (int k = 0; k < 4; ++k) { sv[t * 4 + k] = ov[k]; si[t * 4 + k] = oi[k]; }
    }
    __syncthreads();
  }
}

// ------------------------------------------------------------------
// K_nms_merge: NMS + per-block top4; last block merges + gen_params.
// ------------------------------------------------------------------
__global__ void k_nms_merge(const float* __restrict__ ws_hm, float* __restrict__ candv,
                            int* __restrict__ candi, unsigned int* __restrict__ cnt,
                            const float* __restrict__ out1, const float* __restrict__ params_w,
                            const float* __restrict__ params_b, int* __restrict__ ws_inds,
                            float* __restrict__ ws_gp, float* __restrict__ d_out) {
  __shared__ float sv[256 * 4];
  __shared__ int   si[256 * 4];
  __shared__ int   lastFlag;
  __shared__ float col[4][C_IN];
  int b = blockIdx.x, t = threadIdx.x;

  float v = -1.f; int idx = INT_MAX;
  if (t < 255) {
    int p = b * 255 + t;
    int y = p / HM_W, x = p - y * HM_W;
    float c = ws_hm[p], m = c;
    #pragma unroll
    for (int dy = -1; dy <= 1; ++dy)
      #pragma unroll
      for (int dx = -1; dx <= 1; ++dx) {
        int yy = y + dy, xx = x + dx;
        if (yy >= 0 && yy < HM_H && xx >= 0 && xx < HM_W)
          m = fmaxf(m, ws_hm[yy * HM_W + xx]);
      }
    v = (c == m) ? c : 0.f;
    idx = p;
  }
  sv[t * 4] = v; si[t * 4] = idx;
  #pragma unroll
  for (int k = 1; k < 4; ++k) { sv[t * 4 + k] = -1.f; si[t * 4 + k] = INT_MAX; }
  __syncthreads();
  top4_tree<256>(sv, si, t);
  if (t == 0) {
    #pragma unroll
    for (int k = 0; k < 4; ++k) { candv[b * 4 + k] = sv[k]; candi[b * 4 + k] = si[k]; }
    __threadfence();
    unsigned int tk = atomicAdd(cnt, 1u);
    lastFlag = (tk == 127u);
  }
  __syncthreads();
  if (!lastFlag) return;
  __threadfence();

  if (t < 128) {
    #pragma unroll
    for (int k = 0; k < 4; ++k) { sv[t * 4 + k] = candv[t * 4 + k]; si[t * 4 + k] = candi[t * 4 + k]; }
  }
  __syncthreads();
  top4_tree<128>(sv, si, t);
  if (t == 0) {
    #pragma unroll
    for (int k = 0; k < 4; ++k) {
      d_out[k]     = sv[k];
      d_out[4 + k] = (float)si[k];
      ws_inds[k]   = si[k];
    }
  }
  __syncthreads();

  #pragma unroll
  for (int i = 0; i < NI; ++i) col[i][t] = out1[t * HM_N + si[i]];
  __syncthreads();
  for (int o = t; o < NI * NP; o += 256) {
    int i = o / NP, j = o - i * NP;
    float s = params_b[j];
    #pragma unroll 8
    for (int c = 0; c < C_IN; ++c) s += params_w[j * C_IN + c] * col[i][c];
    ws_gp[i * NP + j] = s;
  }
}

// ------------------------------------------------------------------
// K_conv: MFMA implicit-GEMM conv; staging = global_load_lds DMA from T.
// Tile 8x32 px; LDS stage = 10 rows x 36 x x 32 c bf16 (c-contig, no pad) = 23040 B,
// DMA'd as 24 chunks of 1024 B (6 per wave). Epilogue reuses LDS (stride 66).
// ------------------------------------------------------------------
#define ES 66

__global__ __launch_bounds__(256, 3) void k_conv_mfma(
    const unsigned short* __restrict__ T, const unsigned short* __restrict__ wt,
    const float* __restrict__ mb_b, const float* __restrict__ ws_gp,
    float* __restrict__ d_out) {
  __shared__ unsigned short lds16[16896];   // 33792 B (stage uses 24576 incl. overshoot, epi 33792)

  int tid  = threadIdx.x;
  int lane = tid & 63;
  int w    = tid >> 6;
  int n15  = lane & 15;
  int kq   = lane >> 4;
  int gx0 = blockIdx.x * 32, gy0 = blockIdx.y * 8;

  // DMA chunk descriptors: wave w handles chunks [6w, 6w+6)
  int cbase[6];
  #pragma unroll
  for (int it = 0; it < 6; ++it) {
    int k = w * 6 + it;
    int u = k * 512 + lane * 8;            // ushort index into stage
    int pixl = u >> 5;                     // row*36 + xl
    int c0 = (lane & 3) * 8;
    int row = pixl / 36, xl = pixl - row * 36;
    cbase[it] = ((gy0 + row) * PW + (gx0 + xl)) * 256 + c0;
  }

  // A-frag geometry
  int rrow[4], xbas[4];
  #pragma unroll
  for (int i = 0; i < 4; ++i) {
    int mt = w * 4 + i;
    rrow[i] = mt >> 1;
    xbas[i] = (mt & 1) * 16 + n15;
  }

  f32x4 acc[4][4];
  #pragma unroll
  for (int i = 0; i < 4; ++i)
    #pragma unroll
    for (int nt = 0; nt < 4; ++nt)
      acc[i][nt] = (f32x4){0.f, 0.f, 0.f, 0.f};

  #pragma unroll 1
  for (int g = 0; g < 8; ++g) {
    __syncthreads();                       // previous LDS contents consumed
    const unsigned short* Tg = T + g * 32;
    #pragma unroll
    for (int it = 0; it < 6; ++it)
      dma16(Tg + cbase[it], &lds16[(w * 6 + it) * 512]);
    __syncthreads();                       // drains vmcnt -> DMA landed

    #pragma unroll
    for (int t = 0; t < 9; ++t) {
      int ty = t / 3, tx = t - ty * 3;
      const unsigned short* wb = wt + (g * 9 + t) * 2048 + lane * 8;
      bf16x8 bfrag[4], afrag[4];
      #pragma unroll
      for (int nt = 0; nt < 4; ++nt) bfrag[nt] = *(const bf16x8*)(wb + nt * 512);
      #pragma unroll
      for (int i = 0; i < 4; ++i)
        afrag[i] = *(const bf16x8*)&lds16[((rrow[i] + ty) * 36 + xbas[i] + tx) * 32 + kq * 8];
      #pragma unroll
      for (int i = 0; i < 4; ++i)
        #pragma unroll
        for (int nt = 0; nt < 4; ++nt)
          acc[i][nt] = __builtin_amdgcn_mfma_f32_16x16x32_bf16(afrag[i], bfrag[nt], acc[i][nt], 0, 0, 0);
    }
  }

  // epilogue: bias+relu, acc -> LDS [pixel][channel] bf16
  float bias[4];
  #pragma unroll
  for (int nt = 0; nt < 4; ++nt) bias[nt] = mb_b[nt * 16 + n15];
  __syncthreads();
  #pragma unroll
  for (int i = 0; i < 4; ++i) {
    int mt = w * 4 + i;
    int pbase = (mt >> 1) * 32 + (mt & 1) * 16;
    #pragma unroll
    for (int nt = 0; nt < 4; ++nt)
      #pragma unroll
      for (int reg = 0; reg < 4; ++reg) {
        float vv = fmaxf(acc[i][nt][reg] + bias[nt], 0.f);
        lds16[(pbase + kq * 4 + reg) * ES + nt * 16 + n15] = f2bf(vv);
      }
  }
  __syncthreads();

  // dynamic heads: thread tid owns pixel tid
  int r = tid >> 5, xcol = tid & 31;
  int gy = gy0 + r, gx = gx0 + xcol;
  float xc = -1.f + (2.f / 479.f) * (float)gx;
  float yc = -1.f + (2.f / 271.f) * (float)gy;
  float mres[4] = {0.f, 0.f, 0.f, 0.f};
  float rres[4] = {0.f, 0.f, 0.f, 0.f};
  #pragma unroll 8
  for (int o = 0; o < MB; ++o) {
    float v = b2f(lds16[tid * ES + o]);
    #pragma unroll
    for (int i = 0; i < 4; ++i) {
      mres[i] += ws_gp[i * NP + o] * v;
      rres[i] += ws_gp[i * NP + 67 + o] * v;
    }
  }
  int pix = gy * MW + gx;
  #pragma unroll
  for (int i = 0; i < 4; ++i) {
    const float* g = ws_gp + i * NP;
    d_out[MASK_OFF + i * MN + pix] = mres[i] + g[66]  + g[64]  * xc + g[65]  * yc;
    d_out[REG_OFF  + i * MN + pix] = rres[i] + g[133] + g[131] * xc + g[132] * yc;
  }
}

// ------------------------------------------------------------------
// K_mlp: feat_range MLP (unroll 4 for load ILP)
// ------------------------------------------------------------------
__global__ void k_mlp(const float* __restrict__ masks0, const float* __restrict__ w1,
                      const float* __restrict__ b1, const float* __restrict__ w2,
                      const float* __restrict__ b2, float* __restrict__ d_out) {
  int blk = blockIdx.x;          // i*480 + w
  int i = blk / MW;
  int w = blk - i * MW;
  int k = threadIdx.x;           // 0..63
  const float* mcol = masks0 + i * MN + w;
  float s = b1[k];
  #pragma unroll 1
  for (int h = 0; h < MH; h += 4) {
    float m0 = mcol[h * MW], m1 = mcol[(h + 1) * MW];
    float m2 = mcol[(h + 2) * MW], m3 = mcol[(h + 3) * MW];
    s += m0 * w1[h * HID + k] + m1 * w1[(h + 1) * HID + k]
       + m2 * w1[(h + 2) * HID + k] + m3 * w1[(h + 3) * HID + k];
  }
  s = fmaxf(s, 0.f);
  float o0 = s * w2[k * 2 + 0];
  float o1 = s * w2[k * 2 + 1];
  #pragma unroll
  for (int off = 32; off >= 1; off >>= 1) {
    o0 += __shfl_down(o0, off);
    o1 += __shfl_down(o1, off);
  }
  if (k == 0) {
    d_out[FEAT_OFF + blk * 2 + 0] = o0 + b2[0];
    d_out[FEAT_OFF + blk * 2 + 1] = o1 + b2[1];
  }
}

// ------------------------------------------------------------------
extern "C" void kernel_launch(void* const* d_in, const int* in_sizes, int n_in,
                              void* d_out, int out_size, void* d_ws, size_t ws_size,
                              hipStream_t stream) {
  const float* out0     = (const float*)d_in[0];
  const float* out1     = (const float*)d_in[1];
  const float* hm_w     = (const float*)d_in[2];
  const float* hm_b     = (const float*)d_in[3];
  const float* params_w = (const float*)d_in[4];
  const float* params_b = (const float*)d_in[5];
  const float* mb_w     = (const float*)d_in[6];
  const float* mb_b     = (const float*)d_in[7];
  const float* mlp_w1   = (const float*)d_in[8];
  const float* mlp_b1   = (const float*)d_in[9];
  const float* mlp_w2   = (const float*)d_in[10];
  const float* mlp_b2   = (const float*)d_in[11];

  float* ws      = (float*)d_ws;
  float* ws_hm   = ws + WS_HM;
  float* candv   = ws + WS_CV;
  int*   candi   = (int*)(ws + WS_CI);
  float* ws_gp   = ws + WS_GP;
  int*   ws_inds = (int*)(ws + WS_INDS);
  unsigned int* cnt = (unsigned int*)(ws + WS_CNT);
  unsigned short* ws_wt = (unsigned short*)(ws + WS_WT_F);
  unsigned short* ws_T  = (unsigned short*)(ws + WS_T_F);
  float* out     = (float*)d_out;

  k_pre<<<1785, 256, 0, stream>>>(mb_w, ws_wt, out1, hm_w, hm_b, ws_hm, out0, ws_T, cnt);
  k_nms_merge<<<128, 256, 0, stream>>>(ws_hm, candv, candi, cnt, out1,
                                       params_w, params_b, ws_inds, ws_gp, out);
  dim3 gconv(MW / 32, MH / 8);   // 15 x 34
  k_conv_mfma<<<gconv, 256, 0, stream>>>(ws_T, ws_wt, mb_b, ws_gp, out);
  k_mlp<<<NI * MW, 64, 0, stream>>>(out + MASK_OFF, mlp_w1, mlp_b1, mlp_w2, mlp_b2, out);
}

// Round 7
// 370.255 us; speedup vs baseline: 1.1945x; 1.1945x over previous
//
#include <hip/hip_runtime.h>
#include <hip/hip_bf16.h>
#include <math.h>
#include <limits.h>

// ---- problem constants ----
#define C_IN 256
#define HM_H 136
#define HM_W 240
#define HM_N (HM_H * HM_W)      // 32640
#define MB   64
#define MH   272
#define MW   480
#define MN   (MH * MW)          // 130560
#define NP   134
#define NI   4
#define HID  64
#define PW   484                // padded width of T (pixel-major bf16 tensor)
#define PH   276                // 274 used + 2 slack rows for DMA overshoot

// d_out layout (floats): scores[4] | inds[4] | regs0[4*MN] | masks0[4*MN] | feat[4*480*2]
#define REG_OFF   8
#define MASK_OFF  (8 + NI * MN)
#define FEAT_OFF  (8 + 2 * NI * MN)

// ws layout (floats) — non-overlapping
#define WS_HM   0                         // 32640
#define WS_CV   HM_N                      // 512 cand values
#define WS_CI   (HM_N + 512)              // 512 cand indices
#define WS_GP   (2 * HM_N)                // 536 gen params   [65280,65816)
#define WS_INDS (2 * HM_N + NI * NP)      // 4 ints           [65816,65820)
#define WS_CNT  (WS_INDS + 4)             // 1 uint ticket    [65820,65821)
#define WS_WT_F 65824                     // wt: 147456 ushorts = 73728 floats [65824,139552)
#define WS_T_F  139552                    // T: 276*484*256 ushorts

typedef float  f32x4  __attribute__((ext_vector_type(4)));
typedef short  bf16x8 __attribute__((ext_vector_type(8)));

#define AS1 __attribute__((address_space(1)))
#define AS3 __attribute__((address_space(3)))

__device__ __forceinline__ unsigned short f2bf(float f) {
  unsigned int u = __float_as_uint(f);
  u += 0x7FFFu + ((u >> 16) & 1u);
  return (unsigned short)(u >> 16);
}
__device__ __forceinline__ float b2f(unsigned short h) {
  return __uint_as_float(((unsigned int)h) << 16);
}

// direct global->LDS DMA, 16 B per lane, LDS dest = wave-uniform base + lane*16
__device__ __forceinline__ void dma16(const unsigned short* g, unsigned short* l) {
  __builtin_amdgcn_global_load_lds((const AS1 unsigned int*)g, (AS3 unsigned int*)l, 16, 0, 0);
}

// ------------------------------------------------------------------
// K_pre: fused (a) weight swizzle, (b) hm head, (c) out0 -> T bf16 LDS-tiled
// transpose (coalesced writes), (d) T pad-ring zeroing, (e) ticket reset.
// block ranges: [0,576) wswz | [576,1086) hm | [1086,1596) transpose | [1596,1785) pad
// ------------------------------------------------------------------
__global__ __launch_bounds__(256) void k_pre(
    const float* __restrict__ mb_w, unsigned short* __restrict__ wt,
    const float* __restrict__ out1, const float* __restrict__ hm_w,
    const float* __restrict__ hm_b, float* __restrict__ ws_hm,
    const float* __restrict__ out0, unsigned short* __restrict__ T,
    unsigned int* __restrict__ cnt) {
  __shared__ unsigned short smT[64 * 264];   // 33792 B; hm part reuses as float[256]
  int b = blockIdx.x, t = threadIdx.x;
  if (b == 0 && t == 0) *cnt = 0;
  if (b < 576) {
    int idx = b * 256 + t;                 // 147456 total
    int j    = idx & 7;
    int lane = (idx >> 3) & 63;
    int nt   = (idx >> 9) & 3;
    int gt   = idx >> 11;
    int tp   = gt % 9;
    int g    = gt / 9;
    int n = nt * 16 + (lane & 15);
    int c = g * 32 + (lane >> 4) * 8 + j;
    wt[idx] = f2bf(mb_w[(n * C_IN + c) * 9 + tp]);
  } else if (b < 1086) {
    float* part = (float*)smT;             // [4][64]
    int bb = b - 576;                      // 510 blocks
    int cg = t >> 6, pl = t & 63;
    int p = bb * 64 + pl;
    float s = 0.f;
    #pragma unroll 16
    for (int c = 0; c < 64; ++c)
      s += hm_w[cg * 64 + c] * out1[(cg * 64 + c) * HM_N + p];
    part[cg * 64 + pl] = s;
    __syncthreads();
    if (t < 64) {
      float tot = part[t] + part[64 + t] + part[128 + t] + part[192 + t] + hm_b[0];
      float sig = 1.f / (1.f + expf(-tot));
      sig = fminf(fmaxf(sig, 1e-4f), 1.f - 1e-4f);
      ws_hm[bb * 64 + t] = sig;
    }
  } else if (b < 1596) {
    // LDS-tiled transpose: 4 tiles of 64 px per block
    int bb = b - 1086;                     // 0..509
    int cg = t >> 5, q = t & 31;           // cg: 8 channels concurrently, q: px pair
    #pragma unroll 1
    for (int tile = 0; tile < 4; ++tile) {
      int p0 = bb * 256 + tile * 64;
      // phase 1: coalesced float2 reads over pixels -> LDS [px][c]
      #pragma unroll 4
      for (int o = 0; o < 32; ++o) {
        int c = o * 8 + cg;
        float2 v = *(const float2*)(out0 + c * MN + p0 + 2 * q);
        smT[(2 * q)     * 264 + c] = f2bf(v.x);
        smT[(2 * q + 1) * 264 + c] = f2bf(v.y);
      }
      __syncthreads();
      // phase 2: b128 LDS reads -> contiguous 16B/lane stores into T
      #pragma unroll
      for (int it = 0; it < 8; ++it) {
        int task = it * 256 + t;           // 0..2047 = 64 px x 32 chunks
        int px = task >> 5, ch = task & 31;
        int p = p0 + px;
        int y = p / MW, x = p - y * MW;
        bf16x8 vv = *(const bf16x8*)&smT[px * 264 + ch * 8];
        *(bf16x8*)(T + (size_t)((y + 1) * PW + (x + 1)) * 256 + ch * 8) = vv;
      }
      __syncthreads();
    }
  } else {
    // zero the pad ring: rows 0 & 273 (484 px) + cols 0,481 for rows 1..272
    int i = (b - 1596) * 256 + t;          // 1512 px * 32 uint4 = 48384
    if (i < 48384) {
      int z = i >> 5, q = i & 31;
      int trow, tcol;
      if (z < 484)      { trow = 0;   tcol = z; }
      else if (z < 968) { trow = 273; tcol = z - 484; }
      else {
        int zz = z - 968;                  // 0..543
        trow = 1 + (zz >> 1);
        tcol = (zz & 1) ? 481 : 0;
      }
      *(uint4*)(T + (size_t)(trow * PW + tcol) * 256 + q * 8) = make_uint4(0, 0, 0, 0);
    }
  }
}

// ------------------------------------------------------------------
// top-4 helpers
// ------------------------------------------------------------------
__device__ __forceinline__ bool better(float av, int ai, float bv, int bi) {
  return (av > bv) || (av == bv && ai < bi);
}

template<int NTHR>
__device__ void top4_tree(float* sv, int* si, int t) {
  for (int s = NTHR / 2; s >= 1; s >>= 1) {
    if (t < s) {
      float a[4], b[4]; int ai[4], bj[4];
      #pragma unroll
      for (int k = 0; k < 4; ++k) {
        a[k] = sv[t * 4 + k];        ai[k] = si[t * 4 + k];
        b[k] = sv[(t + s) * 4 + k];  bj[k] = si[(t + s) * 4 + k];
      }
      float ov[4]; int oi[4];
      int i = 0, j = 0;
      #pragma unroll
      for (int k = 0; k < 4; ++k) {
        if (better(a[i], ai[i], b[j], bj[j])) { ov[k] = a[i]; oi[k] = ai[i]; ++i; }
        else                                   { ov[k] = b[j]; oi[k] = bj[j]; ++j; }
      }
      #pragma unroll
      for (int k = 0; k < 4; ++k) { sv[t * 4 + k] = ov[k]; si[t * 4 + k] = oi[k]; }
    }
    __syncthreads();
  }
}

// ------------------------------------------------------------------
// K_nms_merge: NMS + per-block top4; last block merges + gen_params.
// ------------------------------------------------------------------
__global__ void k_nms_merge(const float* __restrict__ ws_hm, float* __restrict__ candv,
                            int* __restrict__ candi, unsigned int* __restrict__ cnt,
                            const float* __restrict__ out1, const float* __restrict__ params_w,
                            const float* __restrict__ params_b, int* __restrict__ ws_inds,
                            float* __restrict__ ws_gp, float* __restrict__ d_out) {
  __shared__ float sv[256 * 4];
  __shared__ int   si[256 * 4];
  __shared__ int   lastFlag;
  __shared__ float col[4][C_IN];
  int b = blockIdx.x, t = threadIdx.x;

  float v = -1.f; int idx = INT_MAX;
  if (t < 255) {
    int p = b * 255 + t;
    int y = p / HM_W, x = p - y * HM_W;
    float c = ws_hm[p], m = c;
    #pragma unroll
    for (int dy = -1; dy <= 1; ++dy)
      #pragma unroll
      for (int dx = -1; dx <= 1; ++dx) {
        int yy = y + dy, xx = x + dx;
        if (yy >= 0 && yy < HM_H && xx >= 0 && xx < HM_W)
          m = fmaxf(m, ws_hm[yy * HM_W + xx]);
      }
    v = (c == m) ? c : 0.f;
    idx = p;
  }
  sv[t * 4] = v; si[t * 4] = idx;
  #pragma unroll
  for (int k = 1; k < 4; ++k) { sv[t * 4 + k] = -1.f; si[t * 4 + k] = INT_MAX; }
  __syncthreads();
  top4_tree<256>(sv, si, t);
  if (t == 0) {
    #pragma unroll
    for (int k = 0; k < 4; ++k) { candv[b * 4 + k] = sv[k]; candi[b * 4 + k] = si[k]; }
    __threadfence();
    unsigned int tk = atomicAdd(cnt, 1u);
    lastFlag = (tk == 127u);
  }
  __syncthreads();
  if (!lastFlag) return;
  __threadfence();

  if (t < 128) {
    #pragma unroll
    for (int k = 0; k < 4; ++k) { sv[t * 4 + k] = candv[t * 4 + k]; si[t * 4 + k] = candi[t * 4 + k]; }
  }
  __syncthreads();
  top4_tree<128>(sv, si, t);
  if (t == 0) {
    #pragma unroll
    for (int k = 0; k < 4; ++k) {
      d_out[k]     = sv[k];
      d_out[4 + k] = (float)si[k];
      ws_inds[k]   = si[k];
    }
  }
  __syncthreads();

  #pragma unroll
  for (int i = 0; i < NI; ++i) col[i][t] = out1[t * HM_N + si[i]];
  __syncthreads();
  for (int o = t; o < NI * NP; o += 256) {
    int i = o / NP, j = o - i * NP;
    float s = params_b[j];
    #pragma unroll 8
    for (int c = 0; c < C_IN; ++c) s += params_w[j * C_IN + c] * col[i][c];
    ws_gp[i * NP + j] = s;
  }
}

// ------------------------------------------------------------------
// K_conv: MFMA implicit-GEMM conv; staging = global_load_lds DMA from T.
// Tile 8x32 px; LDS stage = 10 rows x 36 x x 32 c bf16 (c-contig) = 23040 B,
// DMA'd as 24 chunks of 1024 B (6 per wave). Epilogue reuses LDS (stride 66).
// ------------------------------------------------------------------
#define ES 66

__global__ __launch_bounds__(256, 3) void k_conv_mfma(
    const unsigned short* __restrict__ T, const unsigned short* __restrict__ wt,
    const float* __restrict__ mb_b, const float* __restrict__ ws_gp,
    float* __restrict__ d_out) {
  __shared__ unsigned short lds16[16896];   // 33792 B

  int tid  = threadIdx.x;
  int lane = tid & 63;
  int w    = tid >> 6;
  int n15  = lane & 15;
  int kq   = lane >> 4;
  int gx0 = blockIdx.x * 32, gy0 = blockIdx.y * 8;

  // DMA chunk descriptors: wave w handles chunks [6w, 6w+6)
  int cbase[6];
  #pragma unroll
  for (int it = 0; it < 6; ++it) {
    int k = w * 6 + it;
    int u = k * 512 + lane * 8;            // ushort index into stage
    int pixl = u >> 5;                     // row*36 + xl
    int c0 = (lane & 3) * 8;
    int row = pixl / 36, xl = pixl - row * 36;
    cbase[it] = ((gy0 + row) * PW + (gx0 + xl)) * 256 + c0;
  }

  // A-frag geometry
  int rrow[4], xbas[4];
  #pragma unroll
  for (int i = 0; i < 4; ++i) {
    int mt = w * 4 + i;
    rrow[i] = mt >> 1;
    xbas[i] = (mt & 1) * 16 + n15;
  }

  f32x4 acc[4][4];
  #pragma unroll
  for (int i = 0; i < 4; ++i)
    #pragma unroll
    for (int nt = 0; nt < 4; ++nt)
      acc[i][nt] = (f32x4){0.f, 0.f, 0.f, 0.f};

  #pragma unroll 1
  for (int g = 0; g < 8; ++g) {
    __syncthreads();                       // previous LDS contents consumed
    const unsigned short* Tg = T + g * 32;
    #pragma unroll
    for (int it = 0; it < 6; ++it)
      dma16(Tg + cbase[it], &lds16[(w * 6 + it) * 512]);
    __syncthreads();                       // drains vmcnt -> DMA landed

    #pragma unroll
    for (int t = 0; t < 9; ++t) {
      int ty = t / 3, tx = t - ty * 3;
      const unsigned short* wb = wt + (g * 9 + t) * 2048 + lane * 8;
      bf16x8 bfrag[4], afrag[4];
      #pragma unroll
      for (int nt = 0; nt < 4; ++nt) bfrag[nt] = *(const bf16x8*)(wb + nt * 512);
      #pragma unroll
      for (int i = 0; i < 4; ++i)
        afrag[i] = *(const bf16x8*)&lds16[((rrow[i] + ty) * 36 + xbas[i] + tx) * 32 + kq * 8];
      #pragma unroll
      for (int i = 0; i < 4; ++i)
        #pragma unroll
        for (int nt = 0; nt < 4; ++nt)
          acc[i][nt] = __builtin_amdgcn_mfma_f32_16x16x32_bf16(afrag[i], bfrag[nt], acc[i][nt], 0, 0, 0);
    }
  }

  // epilogue: bias+relu, acc -> LDS [pixel][channel] bf16
  float bias[4];
  #pragma unroll
  for (int nt = 0; nt < 4; ++nt) bias[nt] = mb_b[nt * 16 + n15];
  __syncthreads();
  #pragma unroll
  for (int i = 0; i < 4; ++i) {
    int mt = w * 4 + i;
    int pbase = (mt >> 1) * 32 + (mt & 1) * 16;
    #pragma unroll
    for (int nt = 0; nt < 4; ++nt)
      #pragma unroll
      for (int reg = 0; reg < 4; ++reg) {
        float vv = fmaxf(acc[i][nt][reg] + bias[nt], 0.f);
        lds16[(pbase + kq * 4 + reg) * ES + nt * 16 + n15] = f2bf(vv);
      }
  }
  __syncthreads();

  // dynamic heads: thread tid owns pixel tid
  int r = tid >> 5, xcol = tid & 31;
  int gy = gy0 + r, gx = gx0 + xcol;
  float xc = -1.f + (2.f / 479.f) * (float)gx;
  float yc = -1.f + (2.f / 271.f) * (float)gy;
  float mres[4] = {0.f, 0.f, 0.f, 0.f};
  float rres[4] = {0.f, 0.f, 0.f, 0.f};
  #pragma unroll 8
  for (int o = 0; o < MB; ++o) {
    float v = b2f(lds16[tid * ES + o]);
    #pragma unroll
    for (int i = 0; i < 4; ++i) {
      mres[i] += ws_gp[i * NP + o] * v;
      rres[i] += ws_gp[i * NP + 67 + o] * v;
    }
  }
  int pix = gy * MW + gx;
  #pragma unroll
  for (int i = 0; i < 4; ++i) {
    const float* g = ws_gp + i * NP;
    d_out[MASK_OFF + i * MN + pix] = mres[i] + g[66]  + g[64]  * xc + g[65]  * yc;
    d_out[REG_OFF  + i * MN + pix] = rres[i] + g[133] + g[131] * xc + g[132] * yc;
  }
}

// ------------------------------------------------------------------
// K_mlp: feat_range MLP (unroll 4 for load ILP)
// ------------------------------------------------------------------
__global__ void k_mlp(const float* __restrict__ masks0, const float* __restrict__ w1,
                      const float* __restrict__ b1, const float* __restrict__ w2,
                      const float* __restrict__ b2, float* __restrict__ d_out) {
  int blk = blockIdx.x;          // i*480 + w
  int i = blk / MW;
  int w = blk - i * MW;
  int k = threadIdx.x;           // 0..63
  const float* mcol = masks0 + i * MN + w;
  float s = b1[k];
  #pragma unroll 1
  for (int h = 0; h < MH; h += 4) {
    float m0 = mcol[h * MW], m1 = mcol[(h + 1) * MW];
    float m2 = mcol[(h + 2) * MW], m3 = mcol[(h + 3) * MW];
    s += m0 * w1[h * HID + k] + m1 * w1[(h + 1) * HID + k]
       + m2 * w1[(h + 2) * HID + k] + m3 * w1[(h + 3) * HID + k];
  }
  s = fmaxf(s, 0.f);
  float o0 = s * w2[k * 2 + 0];
  float o1 = s * w2[k * 2 + 1];
  #pragma unroll
  for (int off = 32; off >= 1; off >>= 1) {
    o0 += __shfl_down(o0, off);
    o1 += __shfl_down(o1, off);
  }
  if (k == 0) {
    d_out[FEAT_OFF + blk * 2 + 0] = o0 + b2[0];
    d_out[FEAT_OFF + blk * 2 + 1] = o1 + b2[1];
  }
}

// ------------------------------------------------------------------
extern "C" void kernel_launch(void* const* d_in, const int* in_sizes, int n_in,
                              void* d_out, int out_size, void* d_ws, size_t ws_size,
                              hipStream_t stream) {
  const float* out0     = (const float*)d_in[0];
  const float* out1     = (const float*)d_in[1];
  const float* hm_w     = (const float*)d_in[2];
  const float* hm_b     = (const float*)d_in[3];
  const float* params_w = (const float*)d_in[4];
  const float* params_b = (const float*)d_in[5];
  const float* mb_w     = (const float*)d_in[6];
  const float* mb_b     = (const float*)d_in[7];
  const float* mlp_w1   = (const float*)d_in[8];
  const float* mlp_b1   = (const float*)d_in[9];
  const float* mlp_w2   = (const float*)d_in[10];
  const float* mlp_b2   = (const float*)d_in[11];

  float* ws      = (float*)d_ws;
  float* ws_hm   = ws + WS_HM;
  float* candv   = ws + WS_CV;
  int*   candi   = (int*)(ws + WS_CI);
  float* ws_gp   = ws + WS_GP;
  int*   ws_inds = (int*)(ws + WS_INDS);
  unsigned int* cnt = (unsigned int*)(ws + WS_CNT);
  unsigned short* ws_wt = (unsigned short*)(ws + WS_WT_F);
  unsigned short* ws_T  = (unsigned short*)(ws + WS_T_F);
  float* out     = (float*)d_out;

  k_pre<<<1785, 256, 0, stream>>>(mb_w, ws_wt, out1, hm_w, hm_b, ws_hm, out0, ws_T, cnt);
  k_nms_merge<<<128, 256, 0, stream>>>(ws_hm, candv, candi, cnt, out1,
                                       params_w, params_b, ws_inds, ws_gp, out);
  dim3 gconv(MW / 32, MH / 8);   // 15 x 34
  k_conv_mfma<<<gconv, 256, 0, stream>>>(ws_T, ws_wt, mb_b, ws_gp, out);
  k_mlp<<<NI * MW, 64, 0, stream>>>(out + MASK_OFF, mlp_w1, mlp_b1, mlp_w2, mlp_b2, out);
}